// Round 15
// baseline (1483.688 us; speedup 1.0000x reference)
//
#include <hip/hip_runtime.h>
#include <stdint.h>

typedef unsigned int u32;
typedef unsigned long long u64;

#define Bb 4
#define Nn 8192
#define Dd 64
#define Kk 32
#define MAXIT 30
#define NBLK 256   // 4 batches x 64 blocks; 512 threads = 4 threads/point (dim-quarter-split)
#define RPB  64    // blocks per batch
#define NTH  512

#define ACC_STRIDE 2112  // floats per accumulator row (2048 sums d-major + 32 W + 32 cnt)

// ---- workspace layout (bytes) ----
enum : u32 {
  WS_BAR   = 0u,         // legacy barrier words (zeroed, unused)
  WS_MASKH = 192u,       // [par][4*32] u32 masks of head points (ends 1216)
  WS_TBAR  = 1280u,      // tree barrier: root@+0, flag@+64, leaf[b]@+128+b*64 (ends 1664)
  WS_XHEAD = 34048u,     // 4*32*64 f (ends 66816)
  WS_KEYS1 = 66816u,     // sort keys round 1 (8192 u32)
  WS_KEYS2 = 99584u,
  WS_A1    = 132352u,    // packed (key<<32|idx) u64[8192] round 1 (ends 197888)
  WS_A2    = 197888u,    // packed u64[8192] round 2 (ends 263424)
  WS_ACC   = 263424u,    // [4][2112] f reduced accumulator (single buffer; ends 297216)
  WS_CHG   = 364800u,    // 3 f (global changed-count per buffer); pad to 64
  WS_POBJ  = 364864u,    // [4][64] f
  WS_PMIN  = 365888u,    // [4][32 k][64 blk] u64 packed (dist,idx) (ends 431424)
  WS_DM    = 431424u,    // [4][32][8192] f final distances (ends 4625728)
  WS_PSUM  = 431424u,    // ALIAS of DM during the loop: [4][64][2112] f partials (2.16MB)
  WS_HIST1 = 4625728u,   // 8192 u32 histogram round 1
  WS_HIST2 = 4658496u    // 8192 u32 histogram round 2 (ends 4691264)
};

// Threefry-2x32, 20 rounds — matches jax._src.prng
__device__ __forceinline__ void tf2x32(u32 k0, u32 k1, u32 x0, u32 x1, u32& o0, u32& o1){
  u32 ks2 = k0 ^ k1 ^ 0x1BD11BDAu;
  x0 += k0; x1 += k1;
#define TFR(r) { x0 += x1; x1 = (x1<<(r))|(x1>>(32-(r))); x1 ^= x0; }
  TFR(13) TFR(15) TFR(26) TFR(6)
  x0 += k1;  x1 += ks2 + 1u;
  TFR(17) TFR(29) TFR(16) TFR(24)
  x0 += ks2; x1 += k0 + 2u;
  TFR(13) TFR(15) TFR(26) TFR(6)
  x0 += k0;  x1 += k1 + 3u;
  TFR(17) TFR(29) TFR(16) TFR(24)
  x0 += k1;  x1 += ks2 + 4u;
  TFR(13) TFR(15) TFR(26) TFR(6)
  x0 += ks2; x1 += k0 + 5u;
#undef TFR
  o0 = x0; o1 = x1;
}

// ---------------- tiny zero-init kernel (barriers/CHG/hists) ----------------
__global__ __launch_bounds__(1024, 1) void kzero(char* __restrict__ ws){
  const int tid = threadIdx.x;
  u32* bar   = (u32*)(ws + WS_BAR);
  u32* tbar  = (u32*)(ws + WS_TBAR);
  float* CHG = (float*)(ws + WS_CHG);
  u32* h1 = (u32*)(ws + WS_HIST1);
  u32* h2 = (u32*)(ws + WS_HIST2);
  if (tid < 4) bar[tid] = 0u;
  if (tid < 96) tbar[tid] = 0u;     // root, flag, 4 leaf counters
  if (tid < 3) CHG[tid] = 0.f;
  for (int i = tid; i < 8192; i += 1024){ h1[i] = 0u; h2[i] = 0u; }
}

// device-scope two-level sense-reversing grid barrier (256 co-resident blocks).
// Arrival tree: 64-way per-batch leaf (4 counters, 64B apart) -> 4-way root ->
// release-store of the global flag. Spinners: relaxed poll + ACQUIRE hedge every
// 64 polls; single ACQUIRE agent fence on wake.
__device__ __forceinline__ void grid_barrier(char* ws, int b){
  __syncthreads();
  if (threadIdx.x == 0){
    u32* root = (u32*)(ws + WS_TBAR);
    u32* flag = (u32*)(ws + WS_TBAR + 64);
    u32* leaf = (u32*)(ws + WS_TBAR + 128 + (size_t)b*64);
    u32 g = __hip_atomic_load(flag, __ATOMIC_RELAXED, __HIP_MEMORY_SCOPE_AGENT);
    bool waiter = true;
    u32 a = __hip_atomic_fetch_add(leaf, 1u, __ATOMIC_ACQ_REL, __HIP_MEMORY_SCOPE_AGENT);
    if (a == (u32)(RPB-1)){
      u32 ra = __hip_atomic_fetch_add(root, 1u, __ATOMIC_ACQ_REL, __HIP_MEMORY_SCOPE_AGENT);
      if (ra == (u32)(Bb-1)){
        __hip_atomic_store(root, 0u, __ATOMIC_RELAXED, __HIP_MEMORY_SCOPE_AGENT);
        #pragma unroll
        for (int i = 0; i < Bb; i++)
          __hip_atomic_store((u32*)(ws + WS_TBAR + 128 + (size_t)i*64), 0u,
                             __ATOMIC_RELAXED, __HIP_MEMORY_SCOPE_AGENT);
        __hip_atomic_store(flag, g + 1u, __ATOMIC_RELEASE, __HIP_MEMORY_SCOPE_AGENT);
        waiter = false;
      }
    }
    if (waiter){
      int polls = 0;
      for (;;){
        u32 v = __hip_atomic_load(flag, __ATOMIC_RELAXED, __HIP_MEMORY_SCOPE_AGENT);
        if (v != g) break;
        if ((++polls & 63) == 0){
          v = __hip_atomic_load(flag, __ATOMIC_ACQUIRE, __HIP_MEMORY_SCOPE_AGENT);
          if (v != g) break;
        }
        __builtin_amdgcn_s_sleep(2);
      }
    }
    __builtin_amdgcn_fence(__ATOMIC_ACQUIRE, "agent");
  }
  __syncthreads();
}

// quarter-point (16-dim) square sum
#define CALC_XXH() do { float s0=0.f,s1=0.f,s2=0.f,s3=0.f; \
  _Pragma("unroll") \
  for (int j=0;j<4;j++){ s0+=x[4*j]*x[4*j]; s1+=x[4*j+1]*x[4*j+1]; s2+=x[4*j+2]*x[4*j+2]; s3+=x[4*j+3]*x[4*j+3]; } \
  xxh=(s0+s1)+(s2+s3); } while(0)

// dim-quarter-split dist: each lane does its 16-dim quarter; combine across the
// 4-lane group via 2-step butterfly (xor 1, xor 2). Commutative adds -> all 4
// lanes compute bitwise-identical dloc[k].
#define CALC_DIST() do { \
  float xxf = xxh + __shfl_xor(xxh, 1); \
  xxf += __shfl_xor(xxf, 2); \
  _Pragma("unroll") \
  for (int k=0;k<32;k++){ \
    const float4* cp = (const float4*)&Cl[k*64 + h*16]; \
    float s0=0.f,s1=0.f,s2=0.f,s3=0.f; \
    _Pragma("unroll") \
    for (int j=0;j<4;j++){ float4 c = cp[j]; s0+=x[4*j]*c.x; s1+=x[4*j+1]*c.y; s2+=x[4*j+2]*c.z; s3+=x[4*j+3]*c.w; } \
    float dot=(s0+s1)+(s2+s3); \
    dot += __shfl_xor(dot, 1); \
    dot += __shfl_xor(dot, 2); \
    dloc[k]=(ccl[k]+xxf)-2.f*dot; \
  } } while(0)

__global__ __launch_bounds__(512, 1) void kmain(const float* __restrict__ E, const float* __restrict__ LW,
                                                float* __restrict__ out, char* __restrict__ ws){
  const int tid = threadIdx.x;
  const int bid = blockIdx.x;
  const int b   = bid >> 6;           // batch
  const int r   = bid & 63;           // block-in-batch
  const int h   = tid & 3;            // dim quarter (16 dims each)
  const int pl  = tid >> 2;           // local point 0..127
  const int n   = (r << 7) + pl;      // this group's point

  u32*   maskh = (u32*)(ws + WS_MASKH);
  float* XH    = (float*)(ws + WS_XHEAD);
  u32*   keys1 = (u32*)(ws + WS_KEYS1);
  u32*   keys2 = (u32*)(ws + WS_KEYS2);
  u64*   a1    = (u64*)(ws + WS_A1);
  u64*   a2    = (u64*)(ws + WS_A2);
  u32*   hist1 = (u32*)(ws + WS_HIST1);
  u32*   hist2 = (u32*)(ws + WS_HIST2);
  float* ACC   = (float*)(ws + WS_ACC);
  float* PSUM  = (float*)(ws + WS_PSUM);   // aliases Dm during the loop
  float* CHG   = (float*)(ws + WS_CHG);
  float* Pobj  = (float*)(ws + WS_POBJ);
  u64*   Pmin  = (u64*)(ws + WS_PMIN);
  float* Dm    = (float*)(ws + WS_DM);

  __shared__ float Cl[2048];      // C[k][d] (k-major)
  __shared__ float ccl[32];
  __shared__ __align__(16) float part[ACC_STRIDE]; // sums d-major part[d*32+k]; [2048+k]=W; [2080+k]=cnt
  __shared__ float newX[2048];    // replacement rows staging / rep accumulator / P3 sort scratch
  __shared__ u64   kminl[32];
  __shared__ float red[512];
  __shared__ u32   scan[512];     // prologue scan scratch
  __shared__ u32   sel_s[32];
  __shared__ u32   sh_empty, sh_idx, sh_tcnt;
  __shared__ float sh_chgf, sh_mind;

  // load this thread's 16-dim quarter of its point FIRST (HBM latency hides
  // under the init prologue below)
  float x[16]; float xxh;
  { const float4* xr = (const float4*)(E + (size_t)(b*Nn + n)*Dd + h*16);
    #pragma unroll
    for (int j=0;j<4;j++){ float4 v = xr[j]; x[4*j]=v.x; x[4*j+1]=v.y; x[4*j+2]=v.z; x[4*j+3]=v.w; } }
  CALC_XXH();
  const float w = expf(LW[b*Nn + n]);  // all 4 lanes of the group compute the same w

  // ======== cooperative init prologue (replaces the single-block kinit) ========
  // P0: keys + global histograms + XH init
  {
    const int g = bid*NTH + tid;
    if (g < 8192){
      // key chain (threefry_partitionable=True): root=(0,42); k_init=enc_root(0,0)
      u32 i0,i1; tf2x32(0u,42u, 0u,0u, i0,i1);
      u32 key10,key11, s10,s11;
      tf2x32(i0,i1, 0u,0u, key10,key11);
      tf2x32(i0,i1, 0u,1u, s10,s11);
      u32 s20,s21; tf2x32(key10,key11, 0u,1u, s20,s21);
      u32 y0,y1;
      tf2x32(s10,s11, 0u,(u32)g, y0,y1); u32 k1x = y0 ^ y1;
      tf2x32(s20,s21, 0u,(u32)g, y0,y1); u32 k2x = y0 ^ y1;
      keys1[g] = k1x; keys2[g] = k2x;
      atomicAdd(&hist1[k1x>>19], 1u);
      atomicAdd(&hist2[k2x>>19], 1u);
      XH[g] = E[(size_t)(g>>11)*Nn*Dd + (size_t)(g & 2047)];
    }
  }
  grid_barrier(ws, b);
  // P1: exclusive scan of the two histograms (block 0 -> hist1, block 1 -> hist2)
  if (bid < 2){
    u32* hh = bid ? hist2 : hist1;
    u32 loc[16]; u32 s = 0;
    #pragma unroll
    for (int j = 0; j < 16; j++){ loc[j] = hh[tid*16 + j]; s += loc[j]; }
    scan[tid] = s;
    __syncthreads();
    for (int st = 1; st < 512; st <<= 1){
      u32 v = (tid >= st) ? scan[tid - st] : 0u;
      __syncthreads();
      scan[tid] += v;
      __syncthreads();
    }
    u32 run = tid ? scan[tid-1] : 0u;
    #pragma unroll
    for (int j = 0; j < 16; j++){ u32 c = loc[j]; hh[tid*16 + j] = run; run += c; }
  }
  grid_barrier(ws, b);
  // P2: packed scatter into u64 (key,idx) arrays (hist becomes end-offsets)
  {
    const int g = bid*NTH + tid;
    if (g < 8192){
      u32 kx = keys1[g];
      u32 pos = atomicAdd(&hist1[kx>>19], 1u);
      a1[pos] = ((u64)kx << 32) | (u32)g;
      kx = keys2[g];
      pos = atomicAdd(&hist2[kx>>19], 1u);
      a2[pos] = ((u64)kx << 32) | (u32)g;
    }
  }
  grid_barrier(ws, b);
  // P3: per-bucket sort (order by packed u64 == stable by key). Tiny buckets:
  // batch-load into registers, sort in per-thread LDS slots, write back.
  if (tid < 64){
    int g2 = bid*32 + (tid & 31);
    u64* aa = (tid < 32) ? a1 : a2;
    u32* hh = (tid < 32) ? hist1 : hist2;
    int s0 = g2 ? (int)hh[g2-1] : 0;
    int e0 = (int)hh[g2];
    int m = e0 - s0;
    if (m > 1){
      if (m <= 16){
        u64 tv[16];
        #pragma unroll
        for (int j = 0; j < 16; j++) tv[j] = (j < m) ? aa[s0+j] : ~0ull;
        u64* sc = ((u64*)newX) + (size_t)tid*16;
        #pragma unroll
        for (int j = 0; j < 16; j++){ if (j < m) sc[j] = tv[j]; }
        for (int i2 = 1; i2 < m; i2++){
          u64 kx = sc[i2]; int j = i2-1;
          while (j >= 0 && sc[j] > kx){ sc[j+1] = sc[j]; j--; }
          sc[j+1] = kx;
        }
        #pragma unroll
        for (int j = 0; j < 16; j++){ if (j < m) aa[s0+j] = sc[j]; }
      } else {
        for (int i2 = s0+1; i2 < e0; i2++){
          u64 kx = aa[i2]; int j = i2-1;
          while (j >= s0 && aa[j] > kx){ aa[j+1] = aa[j]; j--; }
          aa[j+1] = kx;
        }
      }
    }
  }
  grid_barrier(ws, b);
  // P4: sel = idx(a1[pos = idx(a2[j])]); load C directly from E
  if (tid < 32){ u32 p = (u32)a2[tid]; sel_s[tid] = (u32)a1[p]; }
  __syncthreads();
  for (int i = tid; i < 2048; i += NTH){
    Cl[i] = E[(size_t)b*Nn*Dd + (size_t)sel_s[i>>6]*Dd + (i & 63)];
  }
  // ======== end prologue ========

  // k_loop = enc_(0,42)(0,1)  (for empty-cluster randint path)
  u32 kl0, kl1; tf2x32(0u,42u, 0u,1u, kl0, kl1);

  __syncthreads();
  if (tid < 32){ float s=0.f; const float* cr=&Cl[tid*64];
    #pragma unroll
    for (int d2=0; d2<64; d2++) s += cr[d2]*cr[d2];
    ccl[tid]=s; }
  __syncthreads();

  u32 prevmask = 0u;
  float dloc[32];

  for (int it = 0; it < MAXIT; it++){
    const int par = it & 1;
    const int cur = it % 3, nxt = (it + 1) % 3;   // triple-buffered CHG scalar
    // ---------- phase 1: assignment + per-block partial sums ----------
    CALC_DIST();
    float mind = dloc[0];
    #pragma unroll
    for (int k=1;k<32;k++) mind = fminf(mind, dloc[k]);
    u32 mask = 0u;
    #pragma unroll
    for (int k=0;k<32;k++) if (fabsf(dloc[k]-mind) < 1e-8f) mask |= (1u<<k);
    int changed = (h==0) ? ((it==0) ? 1 : (mask != prevmask)) : 0;  // count points, not threads
    prevmask = mask;
    if (r == 0 && tid < 128 && h == 0) maskh[par*128 + b*32 + pl] = mask;

    __syncthreads();
    for (int i = tid; i < ACC_STRIDE; i += 512) part[i] = 0.f;
    __syncthreads();
    { u32 mm = mask;
      while (mm){
        int k = __ffs(mm) - 1; mm &= mm - 1;
        #pragma unroll
        for (int d2=0; d2<16; d2++) atomicAdd(&part[(h*16 + d2)*32 + k], w*x[d2]);
        if (h == 0){
          atomicAdd(&part[2048 + k], w);
          atomicAdd(&part[2080 + k], 1.0f);   // count, exact in f32
        }
      } }
    int nchg = __syncthreads_count(changed);
    // publish partials with PLAIN float4 stores (no RMW); CHG keeps its
    // triple-buffered 1-atomic-per-block protocol.
    { float4* dst4 = (float4*)(PSUM + (size_t)(b*64 + r)*ACC_STRIDE);
      const float4* p4 = (const float4*)part;
      dst4[tid] = p4[tid];                          // 512 float4 = 2048 floats
      if (tid < 16) dst4[512 + tid] = p4[512 + tid];// remaining 64 floats
      if (tid == 0 && nchg) unsafeAtomicAdd(&CHG[cur], (float)nchg);
      if (b == 0 && r == 0 && tid == 33) CHG[nxt] = 0.f;
    }
    grid_barrier(ws, b);   // barrier A: all partials + CHG visible

    // ---------- convergence check (uniform across grid) ----------
    if (tid == 0) sh_chgf = CHG[cur];
    __syncthreads();
    if (sh_chgf == 0.f) break;   // global convergence: state frozen (matches reference)

    // ---------- slice-reduce: block r owns elements [r*33, r*33+33) ----------
    // Each wave holds the 64 partials one-per-lane; 6-step shfl_xor butterfly
    // (deterministic order); lane 0 stores the reduced value to ACC.
    { const int wid = tid >> 6, lane = tid & 63;
      const float* pb = PSUM + (size_t)(b*64 + lane)*ACC_STRIDE;
      for (int e = wid; e < 33; e += 8){
        int idx = r*33 + e;
        float v = pb[idx];
        v += __shfl_xor(v, 1);  v += __shfl_xor(v, 2);
        v += __shfl_xor(v, 4);  v += __shfl_xor(v, 8);
        v += __shfl_xor(v, 16); v += __shfl_xor(v, 32);
        if (lane == 0) ACC[(size_t)b*ACC_STRIDE + idx] = v;
      } }
    grid_barrier(ws, b);   // barrier B: reduced ACC visible

    // ---------- phase 2: gather reduced sums; empty flags ----------
    { const float4* s4 = (const float4*)(ACC + (size_t)b*ACC_STRIDE);
      float4* p4 = (float4*)part;
      p4[tid] = s4[tid];
      if (tid < 16) p4[512 + tid] = s4[512 + tid];
      float cv = 1.f;
      if (tid < 128) cv = ACC[(size_t)(tid >> 5)*ACC_STRIDE + 2080 + (tid & 31)];  // all 4x32 counts
      int anyempty = __syncthreads_or(cv == 0.f);   // barrier: part[] now visible

      // own-batch empty mask from reduced counts
      { bool e = (tid < 32) && (part[2080 + tid] == 0.f);
        u64 bal = __ballot(e);
        if (tid == 0) sh_empty = (u32)bal; }
      __syncthreads();
      u32 em = sh_empty;

      if (anyempty){   // uniform across ALL blocks (all batches) -> barrier-safe
        // empty-cluster replacement: X rows j (=cluster idx) replaced BEFORE C update,
        // weights/assignments from pre-replacement X. Each block fixes its local copy.
        u32 g0, g1; tf2x32(kl0, kl1, 0u, (u32)it, g0, g1);   // fold_in(k_loop, it)
        for (int k = 0; k < 32; k++){
          if (!((em >> k) & 1u)) continue;
          int j = b*32 + k;
          u32 y0, y1; tf2x32(g0, g1, 0u, (u32)j, y0, y1);   // partitionable bits: y0^y1
          u32 ridx = (y0 ^ y1) & 8191u;
          u32 mj = maskh[par*128 + b*32 + k];
          float wj = expf(LW[b*Nn + k]);
          if (tid < 64){
            float xo = XH[(b*32 + k)*64 + tid];
            float xn = (ridx < 32u) ? XH[(b*32 + (int)ridx)*64 + tid]
                                    : E[(size_t)(b*Nn + (int)ridx)*Dd + tid];
            newX[k*64 + tid] = xn;
            float dxw = wj * (xn - xo);
            u32 m2 = mj;
            while (m2){ int kq = __ffs(m2) - 1; m2 &= m2 - 1; part[tid*32 + kq] += dxw; }
          }
        }
        __syncthreads();
        grid_barrier(ws, b);    // all fixup reads of old Xhead complete before writes
        if (r == 0){
          for (int k = 0; k < 32; k++){
            if (!((em >> k) & 1u)) continue;
            if (tid < 64) XH[(b*32 + k)*64 + tid] = newX[k*64 + tid];
          }
          __syncthreads();
          if (tid < 128 && ((em >> pl) & 1u)){   // refresh this quarter of replaced head point
            #pragma unroll
            for (int d2 = 0; d2 < 16; d2++) x[d2] = newX[pl*64 + h*16 + d2];
            CALC_XXH();
          }
        }
      }
    }
    __syncthreads();
    // C_new = sums / clip(W, 1e-12)  (empty -> 0, matching reference)
    for (int i = tid; i < 2048; i += 512){
      int k = i >> 6, d = i & 63;
      Cl[i] = part[d*32 + k] / fmaxf(part[2048 + k], 1e-12f);
    }
    __syncthreads();
    if (tid < 32){ float s=0.f; const float* cr=&Cl[tid*64];
      #pragma unroll
      for (int d2=0; d2<64; d2++) s += cr[d2]*cr[d2];
      ccl[tid]=s; }
    __syncthreads();
  }

  // ---------- finalize 1: Dm with final C; ass from LAST assignment; partial mins/obj ----------
  // (Dm overwrites the PSUM alias — PSUM is dead after the loop.)
  CALC_DIST();
  float mind = dloc[0];
  #pragma unroll
  for (int k=1;k<32;k++) mind = fminf(mind, dloc[k]);
  #pragma unroll
  for (int kq=0;kq<8;kq++){                        // quarter-split Dm writes
    int k = h*8 + kq;
    Dm[(size_t)(b*32 + k)*Nn + n] = dloc[k];
  }
  { float4* dst = (float4*)(out + (size_t)(b*Nn + n)*32);
    #pragma unroll
    for (int qq=0;qq<2;qq++){                      // quarter-split mask writes
      int q = h*2 + qq;
      float4 v;
      v.x = ((prevmask>>(4*q  ))&1u) ? 1.f : 0.f;
      v.y = ((prevmask>>(4*q+1))&1u) ? 1.f : 0.f;
      v.z = ((prevmask>>(4*q+2))&1u) ? 1.f : 0.f;
      v.w = ((prevmask>>(4*q+3))&1u) ? 1.f : 0.f;
      dst[q] = v;
    } }
  if (tid < 32) kminl[tid] = ~0ull;
  red[tid] = (h==0) ? mind : 0.f;
  __syncthreads();
  #pragma unroll
  for (int kq=0;kq<8;kq++){                        // quarter-split argmin atomics
    int k = h*8 + kq;
    u32 u = __float_as_uint(dloc[k]);
    u = (u & 0x80000000u) ? ~u : (u | 0x80000000u);  // monotone encode (handles negatives)
    u64 pk = ((u64)u << 32) | (u32)n;                // tie -> smaller n (first argmin)
    atomicMin(&kminl[k], pk);
  }
  for (int s2 = 256; s2 > 0; s2 >>= 1){
    if (tid < s2) red[tid] += red[tid + s2];
    __syncthreads();
  }
  if (tid < 32) Pmin[(size_t)(b*32 + tid)*64 + r] = kminl[tid];
  if (tid == 0) Pobj[b*64 + r] = red[0];
  grid_barrier(ws, b);

  // ---------- finalize 2: first 128 blocks -> (b2,k2): rep_idx, rep, C, obj ----------
  if (bid < 128){
    const int b2 = bid >> 5, k2 = bid & 31;
    const size_t OFF_C    = (size_t)Bb*Nn*Kk;        // 1048576
    const size_t OFF_REP  = OFF_C + (size_t)Bb*Kk*Dd;
    const size_t OFF_RIDX = OFF_REP + (size_t)Bb*Kk*Dd;
    const size_t OFF_OBJ  = OFF_RIDX + (size_t)Bb*Kk;
    if (tid == 0){
      u64 m = ~0ull;
      for (int bl = 0; bl < 64; bl++){ u64 v = Pmin[(size_t)(b2*32 + k2)*64 + bl]; if (v < m) m = v; }
      u32 enc = (u32)(m >> 32);
      u32 ub  = (enc & 0x80000000u) ? (enc & 0x7fffffffu) : ~enc;
      sh_mind = __uint_as_float(ub);
      sh_idx  = (u32)(m & 0xffffffffu);
      sh_tcnt = 0u;
    }
    if (tid < 64) newX[tid] = 0.f;   // rep accumulator
    __syncthreads();
    float mr = sh_mind;
    for (int nn = tid; nn < Nn; nn += 512){
      float dv = Dm[(size_t)(b2*32 + k2)*Nn + nn];
      if (fabsf(dv - mr) < 1e-8f){
        atomicAdd(&sh_tcnt, 1u);
        const float* xr = (nn < 32) ? &XH[(b2*32 + nn)*64] : &E[(size_t)(b2*Nn + nn)*Dd];
        for (int d2 = 0; d2 < 64; d2++) atomicAdd(&newX[d2], xr[d2]);
      }
    }
    __syncthreads();
    if (tid < 64){
      out[OFF_C   + (size_t)(b2*32 + k2)*64 + tid] = Cl[k2*64 + tid];
      out[OFF_REP + (size_t)(b2*32 + k2)*64 + tid] = newX[tid] / (float)sh_tcnt;
    }
    if (tid == 0) out[OFF_RIDX + b2*32 + k2] = (float)sh_idx;
    if (k2 == 0){
      if (tid < 64) red[tid] = Pobj[b2*64 + tid];
      __syncthreads();
      if (tid == 0){ float s = 0.f; for (int i2 = 0; i2 < 64; i2++) s += red[i2];
        out[OFF_OBJ + b2] = s / (float)Nn; }
    }
  }
}

extern "C" void kernel_launch(void* const* d_in, const int* in_sizes, int n_in,
                              void* d_out, int out_size, void* d_ws, size_t ws_size,
                              hipStream_t stream) {
  const float* E  = (const float*)d_in[0];
  const float* LW = (const float*)d_in[1];
  float* out = (float*)d_out;
  char*  ws  = (char*)d_ws;
  (void)in_sizes; (void)n_in; (void)out_size; (void)ws_size;
  kzero<<<dim3(1),    dim3(1024), 0, stream>>>(ws);
  kmain<<<dim3(NBLK), dim3(512),  0, stream>>>(E, LW, out, ws);
}

// Round 16
// 1101.481 us; speedup vs baseline: 1.3470x; 1.3470x over previous
//
#include <hip/hip_runtime.h>
#include <stdint.h>

typedef unsigned int u32;
typedef unsigned long long u64;

#define Bb 4
#define Nn 8192
#define Dd 64
#define Kk 32
#define MAXIT 30
#define NBLK 256   // 4 batches x 64 blocks; 512 threads = 4 threads/point (dim-quarter-split)
#define RPB  64    // blocks per batch
#define NTH  512

#define ACC_STRIDE 2112  // floats per batch accumulator (2048 sums d-major + 32 W + 32 cnt)

// ---- workspace layout (bytes) ----
enum : u32 {
  WS_BAR   = 0u,         // legacy barrier words (zeroed, unused)
  WS_MASKH = 192u,       // [par][4*32] u32 masks of head points (ends 1216)
  WS_TBAR  = 1280u,      // tree barrier: root@+0, flag@+64, leaf[b]@+128+b*64 (ends 1664)
  WS_XHEAD = 34048u,     // 4*32*64 f (ends 66816)
  WS_KEYS1 = 66816u,     // sort keys round 1 (8192 u32)
  WS_KEYS2 = 99584u,
  WS_A1    = 132352u,    // packed (key<<32|idx) u64[8192] round 1 (ends 197888)
  WS_A2    = 197888u,    // packed u64[8192] round 2 (ends 263424)
  WS_ACC   = 263424u,    // 3 x [4][2112] f accumulators; ends 364800
  WS_CHG   = 364800u,    // 3 f (global changed-count per buffer); pad to 64
  WS_POBJ  = 364864u,    // [4][64] f
  WS_PMIN  = 365888u,    // [4][32 k][64 blk] u64 packed (dist,idx) (ends 431424)
  WS_DM    = 431424u,    // [4][32][8192] f final distances (ends 4625728)
  WS_HIST1 = 4625728u,   // 8192 u32 histogram round 1
  WS_HIST2 = 4658496u    // 8192 u32 histogram round 2 (ends 4691264)
};

// Threefry-2x32, 20 rounds — matches jax._src.prng
__device__ __forceinline__ void tf2x32(u32 k0, u32 k1, u32 x0, u32 x1, u32& o0, u32& o1){
  u32 ks2 = k0 ^ k1 ^ 0x1BD11BDAu;
  x0 += k0; x1 += k1;
#define TFR(r) { x0 += x1; x1 = (x1<<(r))|(x1>>(32-(r))); x1 ^= x0; }
  TFR(13) TFR(15) TFR(26) TFR(6)
  x0 += k1;  x1 += ks2 + 1u;
  TFR(17) TFR(29) TFR(16) TFR(24)
  x0 += ks2; x1 += k0 + 2u;
  TFR(13) TFR(15) TFR(26) TFR(6)
  x0 += k0;  x1 += k1 + 3u;
  TFR(17) TFR(29) TFR(16) TFR(24)
  x0 += k1;  x1 += ks2 + 4u;
  TFR(13) TFR(15) TFR(26) TFR(6)
  x0 += ks2; x1 += k0 + 5u;
#undef TFR
  o0 = x0; o1 = x1;
}

// ---------------- tiny zero-init kernel (barriers/CHG/ACC0/hists) ----------------
__global__ __launch_bounds__(1024, 1) void kzero(char* __restrict__ ws){
  const int tid = threadIdx.x;
  u32* bar   = (u32*)(ws + WS_BAR);
  u32* tbar  = (u32*)(ws + WS_TBAR);
  float* CHG = (float*)(ws + WS_CHG);
  float* ACC0 = (float*)(ws + WS_ACC);
  u32* h1 = (u32*)(ws + WS_HIST1);
  u32* h2 = (u32*)(ws + WS_HIST2);
  if (tid < 4) bar[tid] = 0u;
  if (tid < 96) tbar[tid] = 0u;     // root, flag, 4 leaf counters (384 B)
  if (tid < 3) CHG[tid] = 0.f;
  for (int i = tid; i < Bb*ACC_STRIDE; i += 1024) ACC0[i] = 0.f;
  for (int i = tid; i < 8192; i += 1024){ h1[i] = 0u; h2[i] = 0u; }
}

// device-scope two-level sense-reversing grid barrier (256 co-resident blocks).
// Arrival tree: 64-way per-batch leaf (4 counters, 64B apart) -> 4-way root ->
// release-store of the global flag. Cuts same-address arrival RMW serialization
// 256-way -> 64-way. Visibility: block-ACQ_REL(leaf) -> winner-ACQ_REL(root) ->
// root-winner RELEASE(flag) -> spinner relaxed poll + ACQUIRE fence.
__device__ __forceinline__ void grid_barrier(char* ws, int b){
  __syncthreads();
  if (threadIdx.x == 0){
    u32* root = (u32*)(ws + WS_TBAR);
    u32* flag = (u32*)(ws + WS_TBAR + 64);
    u32* leaf = (u32*)(ws + WS_TBAR + 128 + (size_t)b*64);
    u32 g = __hip_atomic_load(flag, __ATOMIC_RELAXED, __HIP_MEMORY_SCOPE_AGENT);
    bool waiter = true;
    u32 a = __hip_atomic_fetch_add(leaf, 1u, __ATOMIC_ACQ_REL, __HIP_MEMORY_SCOPE_AGENT);
    if (a == (u32)(RPB-1)){
      u32 ra = __hip_atomic_fetch_add(root, 1u, __ATOMIC_ACQ_REL, __HIP_MEMORY_SCOPE_AGENT);
      if (ra == (u32)(Bb-1)){
        __hip_atomic_store(root, 0u, __ATOMIC_RELAXED, __HIP_MEMORY_SCOPE_AGENT);
        #pragma unroll
        for (int i = 0; i < Bb; i++)
          __hip_atomic_store((u32*)(ws + WS_TBAR + 128 + (size_t)i*64), 0u,
                             __ATOMIC_RELAXED, __HIP_MEMORY_SCOPE_AGENT);
        __hip_atomic_store(flag, g + 1u, __ATOMIC_RELEASE, __HIP_MEMORY_SCOPE_AGENT);
        waiter = false;
      }
    }
    if (waiter){
      int polls = 0;
      for (;;){
        u32 v = __hip_atomic_load(flag, __ATOMIC_RELAXED, __HIP_MEMORY_SCOPE_AGENT);
        if (v != g) break;
        if ((++polls & 63) == 0){
          v = __hip_atomic_load(flag, __ATOMIC_ACQUIRE, __HIP_MEMORY_SCOPE_AGENT);
          if (v != g) break;
        }
        __builtin_amdgcn_s_sleep(2);
      }
    }
    __builtin_amdgcn_fence(__ATOMIC_ACQUIRE, "agent");
  }
  __syncthreads();
}

// quarter-point (16-dim) square sum
#define CALC_XXH() do { float s0=0.f,s1=0.f,s2=0.f,s3=0.f; \
  _Pragma("unroll") \
  for (int j=0;j<4;j++){ s0+=x[4*j]*x[4*j]; s1+=x[4*j+1]*x[4*j+1]; s2+=x[4*j+2]*x[4*j+2]; s3+=x[4*j+3]*x[4*j+3]; } \
  xxh=(s0+s1)+(s2+s3); } while(0)

// dim-quarter-split dist: each lane does its 16-dim quarter; combine across the
// 4-lane group via 2-step butterfly (xor 1, xor 2). Commutative adds -> all 4
// lanes compute bitwise-identical dloc[k].
// Bank-conflict fix: lanes h>=2 walk their 4 chunks in rotated order jj=(j+2)&3,
// so within each ds_read_b128 instruction the four lanes' 16B reads land on
// pairwise-disjoint bank groups (was a 2-way conflict between h and h+2 on
// every dist load = the session-constant 1.95e7 SQ_LDS_BANK_CONFLICT).
// x[4*jj] pairs with cp[jj] exactly as before; only per-lane chunk-accumulation
// order changes (1-ulp-class reorder).
#define CALC_DIST() do { \
  float xxf = xxh + __shfl_xor(xxh, 1); \
  xxf += __shfl_xor(xxf, 2); \
  const int jph = (h >> 1) << 1; \
  _Pragma("unroll") \
  for (int k=0;k<32;k++){ \
    const float4* cp = (const float4*)&Cl[k*64 + h*16]; \
    float s0=0.f,s1=0.f,s2=0.f,s3=0.f; \
    _Pragma("unroll") \
    for (int j=0;j<4;j++){ int jj=(j+jph)&3; float4 c = cp[jj]; \
      s0+=x[4*jj]*c.x; s1+=x[4*jj+1]*c.y; s2+=x[4*jj+2]*c.z; s3+=x[4*jj+3]*c.w; } \
    float dot=(s0+s1)+(s2+s3); \
    dot += __shfl_xor(dot, 1); \
    dot += __shfl_xor(dot, 2); \
    dloc[k]=(ccl[k]+xxf)-2.f*dot; \
  } } while(0)

__global__ __launch_bounds__(512, 1) void kmain(const float* __restrict__ E, const float* __restrict__ LW,
                                                float* __restrict__ out, char* __restrict__ ws){
  const int tid = threadIdx.x;
  const int bid = blockIdx.x;
  const int b   = bid >> 6;           // batch
  const int r   = bid & 63;           // block-in-batch
  const int h   = tid & 3;            // dim quarter (16 dims each)
  const int pl  = tid >> 2;           // local point 0..127
  const int n   = (r << 7) + pl;      // this group's point

  u32*   maskh = (u32*)(ws + WS_MASKH);
  float* XH    = (float*)(ws + WS_XHEAD);
  u32*   keys1 = (u32*)(ws + WS_KEYS1);
  u32*   keys2 = (u32*)(ws + WS_KEYS2);
  u64*   a1    = (u64*)(ws + WS_A1);
  u64*   a2    = (u64*)(ws + WS_A2);
  u32*   hist1 = (u32*)(ws + WS_HIST1);
  u32*   hist2 = (u32*)(ws + WS_HIST2);
  float* ACC   = (float*)(ws + WS_ACC);
  float* CHG   = (float*)(ws + WS_CHG);
  float* Pobj  = (float*)(ws + WS_POBJ);
  u64*   Pmin  = (u64*)(ws + WS_PMIN);
  float* Dm    = (float*)(ws + WS_DM);

  __shared__ float Cl[2048];      // C[k][d] (k-major)
  __shared__ float ccl[32];
  __shared__ float part[ACC_STRIDE]; // [0..2047] sums d-major part[d*32+k]; [2048+k]=W; [2080+k]=cnt
  __shared__ float newX[2048];    // replacement rows staging / rep accumulator / P3 sort scratch
  __shared__ u64   kminl[32];
  __shared__ float red[512];
  __shared__ u32   scan[512];     // prologue scan scratch
  __shared__ u32   sel_s[32];
  __shared__ u32   sh_empty, sh_idx, sh_tcnt;
  __shared__ float sh_chgf, sh_mind;

  // load this thread's 16-dim quarter of its point FIRST (HBM latency hides
  // under the init prologue below)
  float x[16]; float xxh;
  { const float4* xr = (const float4*)(E + (size_t)(b*Nn + n)*Dd + h*16);
    #pragma unroll
    for (int j=0;j<4;j++){ float4 v = xr[j]; x[4*j]=v.x; x[4*j+1]=v.y; x[4*j+2]=v.z; x[4*j+3]=v.w; } }
  CALC_XXH();
  const float w = expf(LW[b*Nn + n]);  // all 4 lanes of the group compute the same w

  // ======== cooperative init prologue (replaces the single-block kinit) ========
  // P0: keys + global histograms + XH init
  {
    const int g = bid*NTH + tid;
    if (g < 8192){
      // key chain (threefry_partitionable=True): root=(0,42); k_init=enc_root(0,0)
      u32 i0,i1; tf2x32(0u,42u, 0u,0u, i0,i1);
      u32 key10,key11, s10,s11;
      tf2x32(i0,i1, 0u,0u, key10,key11);
      tf2x32(i0,i1, 0u,1u, s10,s11);
      u32 s20,s21; tf2x32(key10,key11, 0u,1u, s20,s21);
      u32 y0,y1;
      tf2x32(s10,s11, 0u,(u32)g, y0,y1); u32 k1x = y0 ^ y1;
      tf2x32(s20,s21, 0u,(u32)g, y0,y1); u32 k2x = y0 ^ y1;
      keys1[g] = k1x; keys2[g] = k2x;
      atomicAdd(&hist1[k1x>>19], 1u);
      atomicAdd(&hist2[k2x>>19], 1u);
      XH[g] = E[(size_t)(g>>11)*Nn*Dd + (size_t)(g & 2047)];
    }
  }
  grid_barrier(ws, b);
  // P1: exclusive scan of the two histograms (block 0 -> hist1, block 1 -> hist2)
  if (bid < 2){
    u32* hh = bid ? hist2 : hist1;
    u32 loc[16]; u32 s = 0;
    #pragma unroll
    for (int j = 0; j < 16; j++){ loc[j] = hh[tid*16 + j]; s += loc[j]; }
    scan[tid] = s;
    __syncthreads();
    for (int st = 1; st < 512; st <<= 1){
      u32 v = (tid >= st) ? scan[tid - st] : 0u;
      __syncthreads();
      scan[tid] += v;
      __syncthreads();
    }
    u32 run = tid ? scan[tid-1] : 0u;
    #pragma unroll
    for (int j = 0; j < 16; j++){ u32 c = loc[j]; hh[tid*16 + j] = run; run += c; }
  }
  grid_barrier(ws, b);
  // P2: packed scatter into u64 (key,idx) arrays (hist becomes end-offsets)
  {
    const int g = bid*NTH + tid;
    if (g < 8192){
      u32 kx = keys1[g];
      u32 pos = atomicAdd(&hist1[kx>>19], 1u);
      a1[pos] = ((u64)kx << 32) | (u32)g;
      kx = keys2[g];
      pos = atomicAdd(&hist2[kx>>19], 1u);
      a2[pos] = ((u64)kx << 32) | (u32)g;
    }
  }
  grid_barrier(ws, b);
  // P3: per-bucket sort (order by packed u64 == stable by key). Buckets are
  // tiny (mean 1, max ~8): batch-load into registers (parallel predicated
  // loads, one waitcnt), sort in per-thread LDS slots (newX reused as u64
  // scratch: 64 threads x 16 slots = 8KB), write back. Global serial fallback
  // for m>16 (never expected; correctness-safe).
  if (tid < 64){
    int g2 = bid*32 + (tid & 31);
    u64* aa = (tid < 32) ? a1 : a2;
    u32* hh = (tid < 32) ? hist1 : hist2;
    int s0 = g2 ? (int)hh[g2-1] : 0;
    int e0 = (int)hh[g2];
    int m = e0 - s0;
    if (m > 1){
      if (m <= 16){
        u64 tv[16];
        #pragma unroll
        for (int j = 0; j < 16; j++) tv[j] = (j < m) ? aa[s0+j] : ~0ull;
        u64* sc = ((u64*)newX) + (size_t)tid*16;
        #pragma unroll
        for (int j = 0; j < 16; j++){ if (j < m) sc[j] = tv[j]; }
        for (int i2 = 1; i2 < m; i2++){
          u64 kx = sc[i2]; int j = i2-1;
          while (j >= 0 && sc[j] > kx){ sc[j+1] = sc[j]; j--; }
          sc[j+1] = kx;
        }
        #pragma unroll
        for (int j = 0; j < 16; j++){ if (j < m) aa[s0+j] = sc[j]; }
      } else {
        for (int i2 = s0+1; i2 < e0; i2++){
          u64 kx = aa[i2]; int j = i2-1;
          while (j >= s0 && aa[j] > kx){ aa[j+1] = aa[j]; j--; }
          aa[j+1] = kx;
        }
      }
    }
  }
  grid_barrier(ws, b);
  // P4: sel = idx(a1[pos = idx(a2[j])]); load C directly from E
  if (tid < 32){ u32 p = (u32)a2[tid]; sel_s[tid] = (u32)a1[p]; }
  __syncthreads();
  for (int i = tid; i < 2048; i += NTH){
    Cl[i] = E[(size_t)b*Nn*Dd + (size_t)sel_s[i>>6]*Dd + (i & 63)];
  }
  // ======== end prologue ========

  // k_loop = enc_(0,42)(0,1)  (for empty-cluster randint path)
  u32 kl0, kl1; tf2x32(0u,42u, 0u,1u, kl0, kl1);

  __syncthreads();
  if (tid < 32){ float s=0.f; const float* cr=&Cl[tid*64];
    #pragma unroll
    for (int d2=0; d2<64; d2++) s += cr[d2]*cr[d2];
    ccl[tid]=s; }
  __syncthreads();

  u32 prevmask = 0u;
  float dloc[32];

  for (int it = 0; it < MAXIT; it++){
    const int par = it & 1;
    const int cur = it % 3, nxt = (it + 1) % 3;   // triple-buffered accumulators
    // ---------- phase 1: assignment + per-block partial sums ----------
    CALC_DIST();
    float mind = dloc[0];
    #pragma unroll
    for (int k=1;k<32;k++) mind = fminf(mind, dloc[k]);
    u32 mask = 0u;
    #pragma unroll
    for (int k=0;k<32;k++) if (fabsf(dloc[k]-mind) < 1e-8f) mask |= (1u<<k);
    int changed = (h==0) ? ((it==0) ? 1 : (mask != prevmask)) : 0;  // count points, not threads
    prevmask = mask;
    if (r == 0 && tid < 128 && h == 0) maskh[par*128 + b*32 + pl] = mask;

    __syncthreads();
    for (int i = tid; i < ACC_STRIDE; i += 512) part[i] = 0.f;
    __syncthreads();
    { u32 mm = mask;
      while (mm){
        int k = __ffs(mm) - 1; mm &= mm - 1;
        #pragma unroll
        for (int d2=0; d2<16; d2++) atomicAdd(&part[(h*16 + d2)*32 + k], w*x[d2]);
        if (h == 0){
          atomicAdd(&part[2048 + k], w);
          atomicAdd(&part[2080 + k], 1.0f);   // count, exact in f32
        }
      } }
    int nchg = __syncthreads_count(changed);
    // scatter partials into the shared per-batch accumulator (native f32 atomics),
    // zero the t+1 buffer (its last readers finished before the t-1 barrier),
    // and add this block's changed-count to the global scalar.
    { float* dst = ACC + (size_t)cur*Bb*ACC_STRIDE + b*ACC_STRIDE;
      for (int i = tid; i < ACC_STRIDE; i += 512) unsafeAtomicAdd(&dst[i], part[i]);
      if (tid == 0 && nchg) unsafeAtomicAdd(&CHG[cur], (float)nchg);
      float* nz = ACC + (size_t)nxt*Bb*ACC_STRIDE + b*ACC_STRIDE;
      if (tid < 33) nz[r*33 + tid] = 0.f;           // 64 blocks x 33 = 2112 exactly
      if (b == 0 && r == 0 && tid == 33) CHG[nxt] = 0.f;
    }
    grid_barrier(ws, b);

    // ---------- phase 2: read reduced sums; global convergence / empty flags ----------
    { const float* src = ACC + (size_t)cur*Bb*ACC_STRIDE;
      for (int i = tid; i < ACC_STRIDE; i += 512) part[i] = src[b*ACC_STRIDE + i];
      float cv = 1.f;
      if (tid < 128) cv = src[(size_t)(tid >> 5)*ACC_STRIDE + 2080 + (tid & 31)];  // all 4x32 counts
      if (tid == 0) sh_chgf = CHG[cur];
      int anyempty = __syncthreads_or(cv == 0.f);   // barrier: part[] now visible
      if (sh_chgf == 0.f) break;   // global convergence: state frozen (matches reference)

      // own-batch empty mask from reduced counts
      { bool e = (tid < 32) && (part[2080 + tid] == 0.f);
        u64 bal = __ballot(e);
        if (tid == 0) sh_empty = (u32)bal; }
      __syncthreads();
      u32 em = sh_empty;

      if (anyempty){   // uniform across ALL blocks (all batches) -> barrier-safe
        // empty-cluster replacement: X rows j (=cluster idx) replaced BEFORE C update,
        // weights/assignments from pre-replacement X. Each block fixes its local copy.
        u32 g0, g1; tf2x32(kl0, kl1, 0u, (u32)it, g0, g1);   // fold_in(k_loop, it)
        for (int k = 0; k < 32; k++){
          if (!((em >> k) & 1u)) continue;
          int j = b*32 + k;
          u32 y0, y1; tf2x32(g0, g1, 0u, (u32)j, y0, y1);   // partitionable bits: y0^y1
          u32 ridx = (y0 ^ y1) & 8191u;
          u32 mj = maskh[par*128 + b*32 + k];
          float wj = expf(LW[b*Nn + k]);
          if (tid < 64){
            float xo = XH[(b*32 + k)*64 + tid];
            float xn = (ridx < 32u) ? XH[(b*32 + (int)ridx)*64 + tid]
                                    : E[(size_t)(b*Nn + (int)ridx)*Dd + tid];
            newX[k*64 + tid] = xn;
            float dxw = wj * (xn - xo);
            u32 m2 = mj;
            while (m2){ int kq = __ffs(m2) - 1; m2 &= m2 - 1; part[tid*32 + kq] += dxw; }
          }
        }
        __syncthreads();
        grid_barrier(ws, b);    // all fixup reads of old Xhead complete before writes
        if (r == 0){
          for (int k = 0; k < 32; k++){
            if (!((em >> k) & 1u)) continue;
            if (tid < 64) XH[(b*32 + k)*64 + tid] = newX[k*64 + tid];
          }
          __syncthreads();
          if (tid < 128 && ((em >> pl) & 1u)){   // refresh this quarter of replaced head point
            #pragma unroll
            for (int d2 = 0; d2 < 16; d2++) x[d2] = newX[pl*64 + h*16 + d2];
            CALC_XXH();
          }
        }
      }
    }
    __syncthreads();
    // C_new = sums / clip(W, 1e-12)  (empty -> 0, matching reference)
    for (int i = tid; i < 2048; i += 512){
      int k = i >> 6, d = i & 63;
      Cl[i] = part[d*32 + k] / fmaxf(part[2048 + k], 1e-12f);
    }
    __syncthreads();
    if (tid < 32){ float s=0.f; const float* cr=&Cl[tid*64];
      #pragma unroll
      for (int d2=0; d2<64; d2++) s += cr[d2]*cr[d2];
      ccl[tid]=s; }
    __syncthreads();
  }

  // ---------- finalize 1: Dm with final C; ass from LAST assignment; partial mins/obj ----------
  CALC_DIST();
  float mind = dloc[0];
  #pragma unroll
  for (int k=1;k<32;k++) mind = fminf(mind, dloc[k]);
  #pragma unroll
  for (int kq=0;kq<8;kq++){                        // quarter-split Dm writes
    int k = h*8 + kq;
    Dm[(size_t)(b*32 + k)*Nn + n] = dloc[k];
  }
  { float4* dst = (float4*)(out + (size_t)(b*Nn + n)*32);
    #pragma unroll
    for (int qq=0;qq<2;qq++){                      // quarter-split mask writes
      int q = h*2 + qq;
      float4 v;
      v.x = ((prevmask>>(4*q  ))&1u) ? 1.f : 0.f;
      v.y = ((prevmask>>(4*q+1))&1u) ? 1.f : 0.f;
      v.z = ((prevmask>>(4*q+2))&1u) ? 1.f : 0.f;
      v.w = ((prevmask>>(4*q+3))&1u) ? 1.f : 0.f;
      dst[q] = v;
    } }
  if (tid < 32) kminl[tid] = ~0ull;
  red[tid] = (h==0) ? mind : 0.f;
  __syncthreads();
  #pragma unroll
  for (int kq=0;kq<8;kq++){                        // quarter-split argmin atomics
    int k = h*8 + kq;
    u32 u = __float_as_uint(dloc[k]);
    u = (u & 0x80000000u) ? ~u : (u | 0x80000000u);  // monotone encode (handles negatives)
    u64 pk = ((u64)u << 32) | (u32)n;                // tie -> smaller n (first argmin)
    atomicMin(&kminl[k], pk);
  }
  for (int s2 = 256; s2 > 0; s2 >>= 1){
    if (tid < s2) red[tid] += red[tid + s2];
    __syncthreads();
  }
  if (tid < 32) Pmin[(size_t)(b*32 + tid)*64 + r] = kminl[tid];
  if (tid == 0) Pobj[b*64 + r] = red[0];
  grid_barrier(ws, b);

  // ---------- finalize 2: first 128 blocks -> (b2,k2): rep_idx, rep, C, obj ----------
  if (bid < 128){
    const int b2 = bid >> 5, k2 = bid & 31;
    const size_t OFF_C    = (size_t)Bb*Nn*Kk;        // 1048576
    const size_t OFF_REP  = OFF_C + (size_t)Bb*Kk*Dd;
    const size_t OFF_RIDX = OFF_REP + (size_t)Bb*Kk*Dd;
    const size_t OFF_OBJ  = OFF_RIDX + (size_t)Bb*Kk;
    if (tid == 0){
      u64 m = ~0ull;
      for (int bl = 0; bl < 64; bl++){ u64 v = Pmin[(size_t)(b2*32 + k2)*64 + bl]; if (v < m) m = v; }
      u32 enc = (u32)(m >> 32);
      u32 ub  = (enc & 0x80000000u) ? (enc & 0x7fffffffu) : ~enc;
      sh_mind = __uint_as_float(ub);
      sh_idx  = (u32)(m & 0xffffffffu);
      sh_tcnt = 0u;
    }
    if (tid < 64) newX[tid] = 0.f;   // rep accumulator
    __syncthreads();
    float mr = sh_mind;
    for (int nn = tid; nn < Nn; nn += 512){
      float dv = Dm[(size_t)(b2*32 + k2)*Nn + nn];
      if (fabsf(dv - mr) < 1e-8f){
        atomicAdd(&sh_tcnt, 1u);
        const float* xr = (nn < 32) ? &XH[(b2*32 + nn)*64] : &E[(size_t)(b2*Nn + nn)*Dd];
        for (int d2 = 0; d2 < 64; d2++) atomicAdd(&newX[d2], xr[d2]);
      }
    }
    __syncthreads();
    if (tid < 64){
      out[OFF_C   + (size_t)(b2*32 + k2)*64 + tid] = Cl[k2*64 + tid];
      out[OFF_REP + (size_t)(b2*32 + k2)*64 + tid] = newX[tid] / (float)sh_tcnt;
    }
    if (tid == 0) out[OFF_RIDX + b2*32 + k2] = (float)sh_idx;
    if (k2 == 0){
      if (tid < 64) red[tid] = Pobj[b2*64 + tid];
      __syncthreads();
      if (tid == 0){ float s = 0.f; for (int i2 = 0; i2 < 64; i2++) s += red[i2];
        out[OFF_OBJ + b2] = s / (float)Nn; }
    }
  }
}

extern "C" void kernel_launch(void* const* d_in, const int* in_sizes, int n_in,
                              void* d_out, int out_size, void* d_ws, size_t ws_size,
                              hipStream_t stream) {
  const float* E  = (const float*)d_in[0];
  const float* LW = (const float*)d_in[1];
  float* out = (float*)d_out;
  char*  ws  = (char*)d_ws;
  (void)in_sizes; (void)n_in; (void)out_size; (void)ws_size;
  kzero<<<dim3(1),    dim3(1024), 0, stream>>>(ws);
  kmain<<<dim3(NBLK), dim3(512),  0, stream>>>(E, LW, out, ws);
}

// Round 17
// 1056.806 us; speedup vs baseline: 1.4039x; 1.0423x over previous
//
#include <hip/hip_runtime.h>
#include <stdint.h>

typedef unsigned int u32;
typedef unsigned long long u64;

#define Bb 4
#define Nn 8192
#define Dd 64
#define Kk 32
#define MAXIT 30
#define NBLK 256   // 4 batches x 64 blocks; 512 threads = 4 threads/point (dim-quarter-split)
#define RPB  64    // blocks per batch
#define NTH  512

#define ACC_STRIDE 2112  // floats per batch accumulator (2048 sums d-major + 32 W + 32 cnt)

// ---- workspace layout (bytes) ----
enum : u32 {
  WS_BAR   = 0u,         // legacy barrier words (zeroed, unused)
  WS_MASKH = 192u,       // [par][4*32] u32 masks of head points (ends 1216)
  WS_TBAR  = 1280u,      // tree barrier: root@+0, flag@+64, leaf[b]@+128+b*64 (ends 1664)
  WS_XHEAD = 34048u,     // 4*32*64 f (ends 66816)
  WS_KEYS1 = 66816u,     // sort keys round 1 (8192 u32)
  WS_KEYS2 = 99584u,
  WS_A1    = 132352u,    // packed (key<<32|idx) u64[8192] round 1 (ends 197888)
  WS_A2    = 197888u,    // packed u64[8192] round 2 (ends 263424)
  WS_ACC   = 263424u,    // 3 x [4][2112] f accumulators; ends 364800
  WS_CHG   = 364800u,    // 3 f (global changed-count per buffer); pad to 64
  WS_POBJ  = 364864u,    // [4][64] f
  WS_PMIN  = 365888u,    // [4][32 k][64 blk] u64 packed (dist,idx) (ends 431424)
  WS_DM    = 431424u,    // [4][32][8192] f final distances (ends 4625728)
  WS_HIST1 = 4625728u,   // 8192 u32 histogram round 1
  WS_HIST2 = 4658496u    // 8192 u32 histogram round 2 (ends 4691264)
};

// Threefry-2x32, 20 rounds — matches jax._src.prng
__device__ __forceinline__ void tf2x32(u32 k0, u32 k1, u32 x0, u32 x1, u32& o0, u32& o1){
  u32 ks2 = k0 ^ k1 ^ 0x1BD11BDAu;
  x0 += k0; x1 += k1;
#define TFR(r) { x0 += x1; x1 = (x1<<(r))|(x1>>(32-(r))); x1 ^= x0; }
  TFR(13) TFR(15) TFR(26) TFR(6)
  x0 += k1;  x1 += ks2 + 1u;
  TFR(17) TFR(29) TFR(16) TFR(24)
  x0 += ks2; x1 += k0 + 2u;
  TFR(13) TFR(15) TFR(26) TFR(6)
  x0 += k0;  x1 += k1 + 3u;
  TFR(17) TFR(29) TFR(16) TFR(24)
  x0 += k1;  x1 += ks2 + 4u;
  TFR(13) TFR(15) TFR(26) TFR(6)
  x0 += ks2; x1 += k0 + 5u;
#undef TFR
  o0 = x0; o1 = x1;
}

// ---------------- tiny zero-init kernel (barriers/CHG/ACC0/hists) ----------------
__global__ __launch_bounds__(1024, 1) void kzero(char* __restrict__ ws){
  const int tid = threadIdx.x;
  u32* bar   = (u32*)(ws + WS_BAR);
  u32* tbar  = (u32*)(ws + WS_TBAR);
  float* CHG = (float*)(ws + WS_CHG);
  float* ACC0 = (float*)(ws + WS_ACC);
  u32* h1 = (u32*)(ws + WS_HIST1);
  u32* h2 = (u32*)(ws + WS_HIST2);
  if (tid < 4) bar[tid] = 0u;
  if (tid < 96) tbar[tid] = 0u;     // root, flag, 4 leaf counters (384 B)
  if (tid < 3) CHG[tid] = 0.f;
  for (int i = tid; i < Bb*ACC_STRIDE; i += 1024) ACC0[i] = 0.f;
  for (int i = tid; i < 8192; i += 1024){ h1[i] = 0u; h2[i] = 0u; }
}

// device-scope two-level sense-reversing grid barrier (256 co-resident blocks).
// Arrival tree: 64-way per-batch leaf (4 counters, 64B apart) -> 4-way root ->
// release-store of the global flag. Cuts same-address arrival RMW serialization
// 256-way -> 64-way. Visibility: block-ACQ_REL(leaf) -> winner-ACQ_REL(root) ->
// root-winner RELEASE(flag) -> spinner relaxed poll + ACQUIRE fence.
__device__ __forceinline__ void grid_barrier(char* ws, int b){
  __syncthreads();
  if (threadIdx.x == 0){
    u32* root = (u32*)(ws + WS_TBAR);
    u32* flag = (u32*)(ws + WS_TBAR + 64);
    u32* leaf = (u32*)(ws + WS_TBAR + 128 + (size_t)b*64);
    u32 g = __hip_atomic_load(flag, __ATOMIC_RELAXED, __HIP_MEMORY_SCOPE_AGENT);
    bool waiter = true;
    u32 a = __hip_atomic_fetch_add(leaf, 1u, __ATOMIC_ACQ_REL, __HIP_MEMORY_SCOPE_AGENT);
    if (a == (u32)(RPB-1)){
      u32 ra = __hip_atomic_fetch_add(root, 1u, __ATOMIC_ACQ_REL, __HIP_MEMORY_SCOPE_AGENT);
      if (ra == (u32)(Bb-1)){
        __hip_atomic_store(root, 0u, __ATOMIC_RELAXED, __HIP_MEMORY_SCOPE_AGENT);
        #pragma unroll
        for (int i = 0; i < Bb; i++)
          __hip_atomic_store((u32*)(ws + WS_TBAR + 128 + (size_t)i*64), 0u,
                             __ATOMIC_RELAXED, __HIP_MEMORY_SCOPE_AGENT);
        __hip_atomic_store(flag, g + 1u, __ATOMIC_RELEASE, __HIP_MEMORY_SCOPE_AGENT);
        waiter = false;
      }
    }
    if (waiter){
      int polls = 0;
      for (;;){
        u32 v = __hip_atomic_load(flag, __ATOMIC_RELAXED, __HIP_MEMORY_SCOPE_AGENT);
        if (v != g) break;
        if ((++polls & 63) == 0){
          v = __hip_atomic_load(flag, __ATOMIC_ACQUIRE, __HIP_MEMORY_SCOPE_AGENT);
          if (v != g) break;
        }
        __builtin_amdgcn_s_sleep(2);
      }
    }
    __builtin_amdgcn_fence(__ATOMIC_ACQUIRE, "agent");
  }
  __syncthreads();
}

// quarter-point (16-dim) square sum
#define CALC_XXH() do { float s0=0.f,s1=0.f,s2=0.f,s3=0.f; \
  _Pragma("unroll") \
  for (int j=0;j<4;j++){ s0+=x[4*j]*x[4*j]; s1+=x[4*j+1]*x[4*j+1]; s2+=x[4*j+2]*x[4*j+2]; s3+=x[4*j+3]*x[4*j+3]; } \
  xxh=(s0+s1)+(s2+s3); } while(0)

// dim-quarter-split dist: each lane does its 16-dim quarter; combine across the
// 4-lane group via 2-step butterfly (xor 1, xor 2). Commutative adds -> all 4
// lanes compute bitwise-identical dloc[k]. (Uniform chunk order: keeps
// wave-uniform ds_read offsets -> immediate-offset b128 codegen; the R16
// lane-rotated variant broke that and cost +8% with zero conflict change.)
#define CALC_DIST() do { \
  float xxf = xxh + __shfl_xor(xxh, 1); \
  xxf += __shfl_xor(xxf, 2); \
  _Pragma("unroll") \
  for (int k=0;k<32;k++){ \
    const float4* cp = (const float4*)&Cl[k*64 + h*16]; \
    float s0=0.f,s1=0.f,s2=0.f,s3=0.f; \
    _Pragma("unroll") \
    for (int j=0;j<4;j++){ float4 c = cp[j]; s0+=x[4*j]*c.x; s1+=x[4*j+1]*c.y; s2+=x[4*j+2]*c.z; s3+=x[4*j+3]*c.w; } \
    float dot=(s0+s1)+(s2+s3); \
    dot += __shfl_xor(dot, 1); \
    dot += __shfl_xor(dot, 2); \
    dloc[k]=(ccl[k]+xxf)-2.f*dot; \
  } } while(0)

__global__ __launch_bounds__(512, 1) void kmain(const float* __restrict__ E, const float* __restrict__ LW,
                                                float* __restrict__ out, char* __restrict__ ws){
  const int tid = threadIdx.x;
  const int bid = blockIdx.x;
  const int b   = bid >> 6;           // batch
  const int r   = bid & 63;           // block-in-batch
  const int h   = tid & 3;            // dim quarter (16 dims each)
  const int pl  = tid >> 2;           // local point 0..127
  const int n   = (r << 7) + pl;      // this group's point

  u32*   maskh = (u32*)(ws + WS_MASKH);
  float* XH    = (float*)(ws + WS_XHEAD);
  u32*   keys1 = (u32*)(ws + WS_KEYS1);
  u32*   keys2 = (u32*)(ws + WS_KEYS2);
  u64*   a1    = (u64*)(ws + WS_A1);
  u64*   a2    = (u64*)(ws + WS_A2);
  u32*   hist1 = (u32*)(ws + WS_HIST1);
  u32*   hist2 = (u32*)(ws + WS_HIST2);
  float* ACC   = (float*)(ws + WS_ACC);
  float* CHG   = (float*)(ws + WS_CHG);
  float* Pobj  = (float*)(ws + WS_POBJ);
  u64*   Pmin  = (u64*)(ws + WS_PMIN);
  float* Dm    = (float*)(ws + WS_DM);

  __shared__ float Cl[2048];      // C[k][d] (k-major)
  __shared__ float ccl[32];
  __shared__ float part[ACC_STRIDE]; // [0..2047] sums d-major part[d*32+k]; [2048+k]=W; [2080+k]=cnt
  __shared__ float newX[2048];    // replacement rows staging / rep accumulator / P3 sort scratch
  __shared__ u64   kminl[32];
  __shared__ float red[512];
  __shared__ u32   scan[512];     // prologue scan scratch
  __shared__ u32   sel_s[32];
  __shared__ u32   sh_empty, sh_idx, sh_tcnt;
  __shared__ float sh_chgf, sh_mind;

  // load this thread's 16-dim quarter of its point FIRST (HBM latency hides
  // under the init prologue below)
  float x[16]; float xxh;
  { const float4* xr = (const float4*)(E + (size_t)(b*Nn + n)*Dd + h*16);
    #pragma unroll
    for (int j=0;j<4;j++){ float4 v = xr[j]; x[4*j]=v.x; x[4*j+1]=v.y; x[4*j+2]=v.z; x[4*j+3]=v.w; } }
  CALC_XXH();
  const float w = expf(LW[b*Nn + n]);  // all 4 lanes of the group compute the same w

  // ======== cooperative init prologue (replaces the single-block kinit) ========
  // P0: keys + global histograms + XH init
  {
    const int g = bid*NTH + tid;
    if (g < 8192){
      // key chain (threefry_partitionable=True): root=(0,42); k_init=enc_root(0,0)
      u32 i0,i1; tf2x32(0u,42u, 0u,0u, i0,i1);
      u32 key10,key11, s10,s11;
      tf2x32(i0,i1, 0u,0u, key10,key11);
      tf2x32(i0,i1, 0u,1u, s10,s11);
      u32 s20,s21; tf2x32(key10,key11, 0u,1u, s20,s21);
      u32 y0,y1;
      tf2x32(s10,s11, 0u,(u32)g, y0,y1); u32 k1x = y0 ^ y1;
      tf2x32(s20,s21, 0u,(u32)g, y0,y1); u32 k2x = y0 ^ y1;
      keys1[g] = k1x; keys2[g] = k2x;
      atomicAdd(&hist1[k1x>>19], 1u);
      atomicAdd(&hist2[k2x>>19], 1u);
      XH[g] = E[(size_t)(g>>11)*Nn*Dd + (size_t)(g & 2047)];
    }
  }
  grid_barrier(ws, b);
  // P1: exclusive scan of the two histograms (block 0 -> hist1, block 1 -> hist2)
  if (bid < 2){
    u32* hh = bid ? hist2 : hist1;
    u32 loc[16]; u32 s = 0;
    #pragma unroll
    for (int j = 0; j < 16; j++){ loc[j] = hh[tid*16 + j]; s += loc[j]; }
    scan[tid] = s;
    __syncthreads();
    for (int st = 1; st < 512; st <<= 1){
      u32 v = (tid >= st) ? scan[tid - st] : 0u;
      __syncthreads();
      scan[tid] += v;
      __syncthreads();
    }
    u32 run = tid ? scan[tid-1] : 0u;
    #pragma unroll
    for (int j = 0; j < 16; j++){ u32 c = loc[j]; hh[tid*16 + j] = run; run += c; }
  }
  grid_barrier(ws, b);
  // P2: packed scatter into u64 (key,idx) arrays (hist becomes end-offsets)
  {
    const int g = bid*NTH + tid;
    if (g < 8192){
      u32 kx = keys1[g];
      u32 pos = atomicAdd(&hist1[kx>>19], 1u);
      a1[pos] = ((u64)kx << 32) | (u32)g;
      kx = keys2[g];
      pos = atomicAdd(&hist2[kx>>19], 1u);
      a2[pos] = ((u64)kx << 32) | (u32)g;
    }
  }
  grid_barrier(ws, b);
  // P3: per-bucket sort (order by packed u64 == stable by key). Buckets are
  // tiny (mean 1, max ~8): batch-load into registers (parallel predicated
  // loads, one waitcnt), sort in per-thread LDS slots (newX reused as u64
  // scratch: 64 threads x 16 slots = 8KB), write back. Global serial fallback
  // for m>16 (never expected; correctness-safe).
  if (tid < 64){
    int g2 = bid*32 + (tid & 31);
    u64* aa = (tid < 32) ? a1 : a2;
    u32* hh = (tid < 32) ? hist1 : hist2;
    int s0 = g2 ? (int)hh[g2-1] : 0;
    int e0 = (int)hh[g2];
    int m = e0 - s0;
    if (m > 1){
      if (m <= 16){
        u64 tv[16];
        #pragma unroll
        for (int j = 0; j < 16; j++) tv[j] = (j < m) ? aa[s0+j] : ~0ull;
        u64* sc = ((u64*)newX) + (size_t)tid*16;
        #pragma unroll
        for (int j = 0; j < 16; j++){ if (j < m) sc[j] = tv[j]; }
        for (int i2 = 1; i2 < m; i2++){
          u64 kx = sc[i2]; int j = i2-1;
          while (j >= 0 && sc[j] > kx){ sc[j+1] = sc[j]; j--; }
          sc[j+1] = kx;
        }
        #pragma unroll
        for (int j = 0; j < 16; j++){ if (j < m) aa[s0+j] = sc[j]; }
      } else {
        for (int i2 = s0+1; i2 < e0; i2++){
          u64 kx = aa[i2]; int j = i2-1;
          while (j >= s0 && aa[j] > kx){ aa[j+1] = aa[j]; j--; }
          aa[j+1] = kx;
        }
      }
    }
  }
  grid_barrier(ws, b);
  // P4: sel = idx(a1[pos = idx(a2[j])]); load C directly from E
  if (tid < 32){ u32 p = (u32)a2[tid]; sel_s[tid] = (u32)a1[p]; }
  __syncthreads();
  for (int i = tid; i < 2048; i += NTH){
    Cl[i] = E[(size_t)b*Nn*Dd + (size_t)sel_s[i>>6]*Dd + (i & 63)];
  }
  // ======== end prologue ========

  // k_loop = enc_(0,42)(0,1)  (for empty-cluster randint path)
  u32 kl0, kl1; tf2x32(0u,42u, 0u,1u, kl0, kl1);

  __syncthreads();
  if (tid < 32){ float s=0.f; const float* cr=&Cl[tid*64];
    #pragma unroll
    for (int d2=0; d2<64; d2++) s += cr[d2]*cr[d2];
    ccl[tid]=s; }
  __syncthreads();

  u32 prevmask = 0u;
  float dloc[32];

  for (int it = 0; it < MAXIT; it++){
    const int par = it & 1;
    const int cur = it % 3, nxt = (it + 1) % 3;   // triple-buffered accumulators
    // ---------- phase 1: assignment + per-block partial sums ----------
    CALC_DIST();
    float mind = dloc[0];
    #pragma unroll
    for (int k=1;k<32;k++) mind = fminf(mind, dloc[k]);
    u32 mask = 0u;
    #pragma unroll
    for (int k=0;k<32;k++) if (fabsf(dloc[k]-mind) < 1e-8f) mask |= (1u<<k);
    int changed = (h==0) ? ((it==0) ? 1 : (mask != prevmask)) : 0;  // count points, not threads
    prevmask = mask;
    if (r == 0 && tid < 128 && h == 0) maskh[par*128 + b*32 + pl] = mask;

    __syncthreads();
    for (int i = tid; i < ACC_STRIDE; i += 512) part[i] = 0.f;
    __syncthreads();
    { u32 mm = mask;
      while (mm){
        int k = __ffs(mm) - 1; mm &= mm - 1;
        #pragma unroll
        for (int d2=0; d2<16; d2++) atomicAdd(&part[(h*16 + d2)*32 + k], w*x[d2]);
        if (h == 0){
          atomicAdd(&part[2048 + k], w);
          atomicAdd(&part[2080 + k], 1.0f);   // count, exact in f32
        }
      } }
    int nchg = __syncthreads_count(changed);
    // scatter partials into the shared per-batch accumulator (native f32 atomics),
    // zero the t+1 buffer (its last readers finished before the t-1 barrier),
    // and add this block's changed-count to the global scalar.
    { float* dst = ACC + (size_t)cur*Bb*ACC_STRIDE + b*ACC_STRIDE;
      for (int i = tid; i < ACC_STRIDE; i += 512) unsafeAtomicAdd(&dst[i], part[i]);
      if (tid == 0 && nchg) unsafeAtomicAdd(&CHG[cur], (float)nchg);
      float* nz = ACC + (size_t)nxt*Bb*ACC_STRIDE + b*ACC_STRIDE;
      if (tid < 33) nz[r*33 + tid] = 0.f;           // 64 blocks x 33 = 2112 exactly
      if (b == 0 && r == 0 && tid == 33) CHG[nxt] = 0.f;
    }
    grid_barrier(ws, b);

    // ---------- phase 2: read reduced sums; global convergence / empty flags ----------
    { const float* src = ACC + (size_t)cur*Bb*ACC_STRIDE;
      for (int i = tid; i < ACC_STRIDE; i += 512) part[i] = src[b*ACC_STRIDE + i];
      float cv = 1.f;
      if (tid < 128) cv = src[(size_t)(tid >> 5)*ACC_STRIDE + 2080 + (tid & 31)];  // all 4x32 counts
      if (tid == 0) sh_chgf = CHG[cur];
      int anyempty = __syncthreads_or(cv == 0.f);   // barrier: part[] now visible
      if (sh_chgf == 0.f) break;   // global convergence: state frozen (matches reference)

      // own-batch empty mask from reduced counts
      { bool e = (tid < 32) && (part[2080 + tid] == 0.f);
        u64 bal = __ballot(e);
        if (tid == 0) sh_empty = (u32)bal; }
      __syncthreads();
      u32 em = sh_empty;

      if (anyempty){   // uniform across ALL blocks (all batches) -> barrier-safe
        // empty-cluster replacement: X rows j (=cluster idx) replaced BEFORE C update,
        // weights/assignments from pre-replacement X. Each block fixes its local copy.
        u32 g0, g1; tf2x32(kl0, kl1, 0u, (u32)it, g0, g1);   // fold_in(k_loop, it)
        for (int k = 0; k < 32; k++){
          if (!((em >> k) & 1u)) continue;
          int j = b*32 + k;
          u32 y0, y1; tf2x32(g0, g1, 0u, (u32)j, y0, y1);   // partitionable bits: y0^y1
          u32 ridx = (y0 ^ y1) & 8191u;
          u32 mj = maskh[par*128 + b*32 + k];
          float wj = expf(LW[b*Nn + k]);
          if (tid < 64){
            float xo = XH[(b*32 + k)*64 + tid];
            float xn = (ridx < 32u) ? XH[(b*32 + (int)ridx)*64 + tid]
                                    : E[(size_t)(b*Nn + (int)ridx)*Dd + tid];
            newX[k*64 + tid] = xn;
            float dxw = wj * (xn - xo);
            u32 m2 = mj;
            while (m2){ int kq = __ffs(m2) - 1; m2 &= m2 - 1; part[tid*32 + kq] += dxw; }
          }
        }
        __syncthreads();
        grid_barrier(ws, b);    // all fixup reads of old Xhead complete before writes
        if (r == 0){
          for (int k = 0; k < 32; k++){
            if (!((em >> k) & 1u)) continue;
            if (tid < 64) XH[(b*32 + k)*64 + tid] = newX[k*64 + tid];
          }
          __syncthreads();
          if (tid < 128 && ((em >> pl) & 1u)){   // refresh this quarter of replaced head point
            #pragma unroll
            for (int d2 = 0; d2 < 16; d2++) x[d2] = newX[pl*64 + h*16 + d2];
            CALC_XXH();
          }
        }
      }
    }
    __syncthreads();
    // C_new = sums / clip(W, 1e-12)  (empty -> 0, matching reference)
    for (int i = tid; i < 2048; i += 512){
      int k = i >> 6, d = i & 63;
      Cl[i] = part[d*32 + k] / fmaxf(part[2048 + k], 1e-12f);
    }
    __syncthreads();
    if (tid < 32){ float s=0.f; const float* cr=&Cl[tid*64];
      #pragma unroll
      for (int d2=0; d2<64; d2++) s += cr[d2]*cr[d2];
      ccl[tid]=s; }
    __syncthreads();
  }

  // ---------- finalize 1: Dm with final C; ass from LAST assignment; partial mins/obj ----------
  CALC_DIST();
  float mind = dloc[0];
  #pragma unroll
  for (int k=1;k<32;k++) mind = fminf(mind, dloc[k]);
  #pragma unroll
  for (int kq=0;kq<8;kq++){                        // quarter-split Dm writes
    int k = h*8 + kq;
    Dm[(size_t)(b*32 + k)*Nn + n] = dloc[k];
  }
  { float4* dst = (float4*)(out + (size_t)(b*Nn + n)*32);
    #pragma unroll
    for (int qq=0;qq<2;qq++){                      // quarter-split mask writes
      int q = h*2 + qq;
      float4 v;
      v.x = ((prevmask>>(4*q  ))&1u) ? 1.f : 0.f;
      v.y = ((prevmask>>(4*q+1))&1u) ? 1.f : 0.f;
      v.z = ((prevmask>>(4*q+2))&1u) ? 1.f : 0.f;
      v.w = ((prevmask>>(4*q+3))&1u) ? 1.f : 0.f;
      dst[q] = v;
    } }
  if (tid < 32) kminl[tid] = ~0ull;
  red[tid] = (h==0) ? mind : 0.f;
  __syncthreads();
  #pragma unroll
  for (int kq=0;kq<8;kq++){                        // quarter-split argmin atomics
    int k = h*8 + kq;
    u32 u = __float_as_uint(dloc[k]);
    u = (u & 0x80000000u) ? ~u : (u | 0x80000000u);  // monotone encode (handles negatives)
    u64 pk = ((u64)u << 32) | (u32)n;                // tie -> smaller n (first argmin)
    atomicMin(&kminl[k], pk);
  }
  for (int s2 = 256; s2 > 0; s2 >>= 1){
    if (tid < s2) red[tid] += red[tid + s2];
    __syncthreads();
  }
  if (tid < 32) Pmin[(size_t)(b*32 + tid)*64 + r] = kminl[tid];
  if (tid == 0) Pobj[b*64 + r] = red[0];
  grid_barrier(ws, b);

  // ---------- finalize 2: first 128 blocks -> (b2,k2): rep_idx, rep, C, obj ----------
  if (bid < 128){
    const int b2 = bid >> 5, k2 = bid & 31;
    const size_t OFF_C    = (size_t)Bb*Nn*Kk;        // 1048576
    const size_t OFF_REP  = OFF_C + (size_t)Bb*Kk*Dd;
    const size_t OFF_RIDX = OFF_REP + (size_t)Bb*Kk*Dd;
    const size_t OFF_OBJ  = OFF_RIDX + (size_t)Bb*Kk;
    if (tid == 0){
      u64 m = ~0ull;
      for (int bl = 0; bl < 64; bl++){ u64 v = Pmin[(size_t)(b2*32 + k2)*64 + bl]; if (v < m) m = v; }
      u32 enc = (u32)(m >> 32);
      u32 ub  = (enc & 0x80000000u) ? (enc & 0x7fffffffu) : ~enc;
      sh_mind = __uint_as_float(ub);
      sh_idx  = (u32)(m & 0xffffffffu);
      sh_tcnt = 0u;
    }
    if (tid < 64) newX[tid] = 0.f;   // rep accumulator
    __syncthreads();
    float mr = sh_mind;
    for (int nn = tid; nn < Nn; nn += 512){
      float dv = Dm[(size_t)(b2*32 + k2)*Nn + nn];
      if (fabsf(dv - mr) < 1e-8f){
        atomicAdd(&sh_tcnt, 1u);
        const float* xr = (nn < 32) ? &XH[(b2*32 + nn)*64] : &E[(size_t)(b2*Nn + nn)*Dd];
        for (int d2 = 0; d2 < 64; d2++) atomicAdd(&newX[d2], xr[d2]);
      }
    }
    __syncthreads();
    if (tid < 64){
      out[OFF_C   + (size_t)(b2*32 + k2)*64 + tid] = Cl[k2*64 + tid];
      out[OFF_REP + (size_t)(b2*32 + k2)*64 + tid] = newX[tid] / (float)sh_tcnt;
    }
    if (tid == 0) out[OFF_RIDX + b2*32 + k2] = (float)sh_idx;
    if (k2 == 0){
      if (tid < 64) red[tid] = Pobj[b2*64 + tid];
      __syncthreads();
      if (tid == 0){ float s = 0.f; for (int i2 = 0; i2 < 64; i2++) s += red[i2];
        out[OFF_OBJ + b2] = s / (float)Nn; }
    }
  }
}

extern "C" void kernel_launch(void* const* d_in, const int* in_sizes, int n_in,
                              void* d_out, int out_size, void* d_ws, size_t ws_size,
                              hipStream_t stream) {
  const float* E  = (const float*)d_in[0];
  const float* LW = (const float*)d_in[1];
  float* out = (float*)d_out;
  char*  ws  = (char*)d_ws;
  (void)in_sizes; (void)n_in; (void)out_size; (void)ws_size;
  kzero<<<dim3(1),    dim3(1024), 0, stream>>>(ws);
  kmain<<<dim3(NBLK), dim3(512),  0, stream>>>(E, LW, out, ws);
}